// Round 6
// baseline (130.747 us; speedup 1.0000x reference)
//
#include <hip/hip_runtime.h>
#include <math.h>

#define NQ 10
#define NPAR 100
#define FDIM 256
#define BATCH 256
#define NOUT 30
#define TWO_PI_F 6.283185307179586f
#define LB 5   // lane bits per sim: 32-lane half-wave holds one sim

// Round 6 layout: amp index i (10 bits): bits [4:0] -> lane[4:0], bits [9:5] ->
// register slot a (32 float2 per lane). Lane bit 5 = sim select (2 sims/wave,
// same branch, batch items 2b and 2b+1 -> W/bias/base wave-uniform).
// Wire w (PennyLane MSB-first) <-> bit (9 - w): wires 5..9 = lane bits 4..0,
// wires 0..4 = reg bits 4..0. All cross-lane masks are 1,2,4,8,16: DPP for
// 1,2,8 (VALU pipe), ds_swizzle for 4,16 (32-lane groups). No bpermute left.

template<int MASK>
__device__ __forceinline__ float lx(float v) {
    if constexpr (MASK == 1) {
        return __int_as_float(__builtin_amdgcn_update_dpp(
            0, __float_as_int(v), 0xB1, 0xF, 0xF, true));   // quad_perm [1,0,3,2]
    } else if constexpr (MASK == 2) {
        return __int_as_float(__builtin_amdgcn_update_dpp(
            0, __float_as_int(v), 0x4E, 0xF, 0xF, true));   // quad_perm [2,3,0,1]
    } else if constexpr (MASK == 8) {
        return __int_as_float(__builtin_amdgcn_update_dpp(
            0, __float_as_int(v), 0x128, 0xF, 0xF, true));  // row_ror:8 == xor 8
    } else if constexpr (MASK == 4) {
        return __int_as_float(__builtin_amdgcn_ds_swizzle(__float_as_int(v), 0x101F));
    } else {
        return __int_as_float(__builtin_amdgcn_ds_swizzle(__float_as_int(v), 0x401F));
    }
}

template<int MASK>
__device__ __forceinline__ float2 lx2(float2 v) {
    return make_float2(lx<MASK>(v.x), lx<MASK>(v.y));
}

__device__ __forceinline__ float redAll(float v) {
    v += lx<1>(v);  v += lx<2>(v);  v += lx<4>(v);
    v += lx<8>(v);  v += lx<16>(v);
    return v;                      // sum over the 32-lane half-wave
}

__device__ __forceinline__ float2 cmul(float2 a, float2 b) {
    return make_float2(a.x*b.x - a.y*b.y, a.x*b.y + a.y*b.x);
}

// ---- fused 1-qubit gate U = Rz*Ry*Rx on bit BIT ----
template<int BIT>
__device__ __forceinline__ void gate1q(float2 (&st)[32], int slane,
                                       float2 u00, float2 u01, float2 u10, float2 u11)
{
    if constexpr (BIT >= LB) {
        constexpr int rb = 1 << (BIT - LB);
        #pragma unroll
        for (int a = 0; a < 32; ++a) {
            if (a & rb) continue;
            const int a1 = a | rb;
            const float2 A0 = st[a], A1 = st[a1];
            float2 n0, n1;
            n0.x = u00.x*A0.x - u00.y*A0.y + u01.x*A1.x - u01.y*A1.y;
            n0.y = u00.x*A0.y + u00.y*A0.x + u01.x*A1.y + u01.y*A1.x;
            n1.x = u10.x*A0.x - u10.y*A0.y + u11.x*A1.x - u11.y*A1.y;
            n1.y = u10.x*A0.y + u10.y*A0.x + u11.x*A1.y + u11.y*A1.x;
            st[a] = n0; st[a1] = n1;
        }
    } else {
        constexpr int lb = 1 << BIT;
        const bool hi = (slane & lb) != 0;
        const float2 A = hi ? u11 : u00;
        const float2 B = hi ? u10 : u01;
        #pragma unroll
        for (int g = 0; g < 32; g += 4) {
            const float2 p0 = lx2<lb>(st[g+0]);
            const float2 p1 = lx2<lb>(st[g+1]);
            const float2 p2 = lx2<lb>(st[g+2]);
            const float2 p3 = lx2<lb>(st[g+3]);
            const float2 m0 = st[g+0], m1 = st[g+1], m2 = st[g+2], m3 = st[g+3];
            st[g+0] = make_float2(A.x*m0.x - A.y*m0.y + B.x*p0.x - B.y*p0.y,
                                  A.x*m0.y + A.y*m0.x + B.x*p0.y + B.y*p0.x);
            st[g+1] = make_float2(A.x*m1.x - A.y*m1.y + B.x*p1.x - B.y*p1.y,
                                  A.x*m1.y + A.y*m1.x + B.x*p1.y + B.y*p1.x);
            st[g+2] = make_float2(A.x*m2.x - A.y*m2.y + B.x*p2.x - B.y*p2.y,
                                  A.x*m2.y + A.y*m2.x + B.x*p2.y + B.y*p2.x);
            st[g+3] = make_float2(A.x*m3.x - A.y*m3.y + B.x*p3.x - B.y*p3.y,
                                  A.x*m3.y + A.y*m3.x + B.x*p3.y + B.y*p3.x);
        }
    }
}

// ---- CRX(theta) control bit BC, target bit BT; c=cos(t/2), s=sin(t/2) ----
template<int BC, int BT>
__device__ __forceinline__ void crx(float2 (&st)[32], int slane, float c, float s)
{
    if constexpr (BT >= LB) {
        constexpr int rt = 1 << (BT - LB);
        if constexpr (BC >= LB) {
            constexpr int rc = 1 << (BC - LB);
            #pragma unroll
            for (int a = 0; a < 32; ++a) {
                if (!(a & rc) || (a & rt)) continue;
                const int a1 = a | rt;
                const float2 A0 = st[a], A1 = st[a1];
                float2 n0, n1;
                n0.x = c*A0.x + s*A1.y;  n0.y = c*A0.y - s*A1.x;
                n1.x = c*A1.x + s*A0.y;  n1.y = c*A1.y - s*A0.x;
                st[a] = n0; st[a1] = n1;
            }
        } else {
            constexpr int lc = 1 << BC;
            const bool act = (slane & lc) != 0;
            const float cc = act ? c : 1.f;
            const float ss = act ? s : 0.f;
            #pragma unroll
            for (int a = 0; a < 32; ++a) {
                if (a & rt) continue;
                const int a1 = a | rt;
                const float2 A0 = st[a], A1 = st[a1];
                float2 n0, n1;
                n0.x = cc*A0.x + ss*A1.y;  n0.y = cc*A0.y - ss*A1.x;
                n1.x = cc*A1.x + ss*A0.y;  n1.y = cc*A1.y - ss*A0.x;
                st[a] = n0; st[a1] = n1;
            }
        }
    } else {
        constexpr int lt = 1 << BT;
        if constexpr (BC >= LB) {
            // register-bit control: 16 active slots (a & rc), grouped 4
            constexpr int rc = 1 << (BC - LB);
            #pragma unroll
            for (int j = 0; j < 16; j += 4) {
                const int a0 = ((j     & ~(rc-1)) << 1) | rc | ((j  ) & (rc-1));
                const int a1 = (((j+1) & ~(rc-1)) << 1) | rc | ((j+1) & (rc-1));
                const int a2 = (((j+2) & ~(rc-1)) << 1) | rc | ((j+2) & (rc-1));
                const int a3 = (((j+3) & ~(rc-1)) << 1) | rc | ((j+3) & (rc-1));
                const float2 p0 = lx2<lt>(st[a0]);
                const float2 p1 = lx2<lt>(st[a1]);
                const float2 p2 = lx2<lt>(st[a2]);
                const float2 p3 = lx2<lt>(st[a3]);
                const float2 m0 = st[a0], m1 = st[a1], m2 = st[a2], m3 = st[a3];
                st[a0] = make_float2(c*m0.x + s*p0.y, c*m0.y - s*p0.x);
                st[a1] = make_float2(c*m1.x + s*p1.y, c*m1.y - s*p1.x);
                st[a2] = make_float2(c*m2.x + s*p2.y, c*m2.y - s*p2.x);
                st[a3] = make_float2(c*m3.x + s*p3.y, c*m3.y - s*p3.x);
            }
        } else {
            constexpr int lc = 1 << BC;
            const bool act = (slane & lc) != 0;
            const float cc = act ? c : 1.f;
            const float ss = act ? s : 0.f;
            #pragma unroll
            for (int g = 0; g < 32; g += 4) {
                const float2 p0 = lx2<lt>(st[g+0]);
                const float2 p1 = lx2<lt>(st[g+1]);
                const float2 p2 = lx2<lt>(st[g+2]);
                const float2 p3 = lx2<lt>(st[g+3]);
                const float2 m0 = st[g+0], m1 = st[g+1], m2 = st[g+2], m3 = st[g+3];
                st[g+0] = make_float2(cc*m0.x + ss*p0.y, cc*m0.y - ss*p0.x);
                st[g+1] = make_float2(cc*m1.x + ss*p1.y, cc*m1.y - ss*p1.x);
                st[g+2] = make_float2(cc*m2.x + ss*p2.y, cc*m2.y - ss*p2.x);
                st[g+3] = make_float2(cc*m3.x + ss*p3.y, cc*m3.y - ss*p3.x);
            }
        }
    }
}

// ---- recursive circuit drivers (compile-time q) ----
template<int Q>
__device__ __forceinline__ void layer1q(float2 (&st)[32], int slane, const float2* cs, int idx)
{
    if constexpr (Q < NQ) {
        const float2 X = cs[idx], Y = cs[idx + 1], Z = cs[idx + 2];
        const float cx = X.x, sx = X.y, cy = Y.x, sy = Y.y, cz = Z.x, sz = Z.y;
        const float2 m00 = make_float2( cy*cx,  sy*sx);
        const float2 m01 = make_float2(-sy*cx, -cy*sx);
        const float2 m10 = make_float2( sy*cx, -cy*sx);
        const float2 m11 = make_float2( cy*cx, -sy*sx);
        const float2 u00 = make_float2(cz*m00.x + sz*m00.y, cz*m00.y - sz*m00.x);
        const float2 u01 = make_float2(cz*m01.x + sz*m01.y, cz*m01.y - sz*m01.x);
        const float2 u10 = make_float2(cz*m10.x - sz*m10.y, cz*m10.y + sz*m10.x);
        const float2 u11 = make_float2(cz*m11.x - sz*m11.y, cz*m11.y + sz*m11.x);
        gate1q<9 - Q>(st, slane, u00, u01, u10, u11);
        layer1q<Q + 1>(st, slane, cs, idx + 3);
    }
}

template<int Q>
__device__ __forceinline__ void ringF(float2 (&st)[32], int slane, const float2* cs, int idx)
{
    if constexpr (Q < NQ) {
        const float2 p = cs[idx];
        crx<9 - Q, 9 - ((Q + 1) % NQ)>(st, slane, p.x, p.y);
        ringF<Q + 1>(st, slane, cs, idx + 1);
    }
}

template<int Q>
__device__ __forceinline__ void ringB(float2 (&st)[32], int slane, const float2* cs, int idx)
{
    if constexpr (Q >= 0) {
        const float2 p = cs[idx];
        crx<9 - Q, 9 - ((Q + NQ - 1) % NQ)>(st, slane, p.x, p.y);
        ringB<Q - 1>(st, slane, cs, idx + 1);
    }
}

// ---- column 0 of fused U = Rz*Ry*Rx (product-state init; verified r3-r5) ----
__device__ __forceinline__ void col0(const float2* cs, int w, float2& u00, float2& u10)
{
    const float2 X = cs[3*w], Y = cs[3*w + 1], Z = cs[3*w + 2];
    const float cx = X.x, sx = X.y, cy = Y.x, sy = Y.y, cz = Z.x, sz = Z.y;
    const float2 m00 = make_float2(cy*cx,  sy*sx);
    const float2 m10 = make_float2(sy*cx, -cy*sx);
    u00 = make_float2(cz*m00.x + sz*m00.y, cz*m00.y - sz*m00.x);
    u10 = make_float2(cz*m10.x - sz*m10.y, cz*m10.y + sz*m10.x);
}

// ---- measurements (reduction over the 32-lane half-wave) ----
template<int W>
__device__ __forceinline__ void measureAll(const float2 (&st)[32], int slane, float* m_row)
{
    if constexpr (W < NQ) {
        constexpr int B = 9 - W;
        float sre = 0.f, smm = 0.f, szz = 0.f;
        if constexpr (B >= LB) {
            constexpr int rb = 1 << (B - LB);
            #pragma unroll
            for (int a = 0; a < 32; ++a) {
                if (a & rb) continue;
                const int a1 = a | rb;
                const float2 A0 = st[a], A1 = st[a1];
                sre += A0.x*A1.x + A0.y*A1.y;
                smm += A0.x*A1.y - A0.y*A1.x;
                szz += A0.x*A0.x + A0.y*A0.y - A1.x*A1.x - A1.y*A1.y;
            }
            sre *= 2.f; smm *= 2.f;
        } else {
            constexpr int lb = 1 << B;
            const float sgn = (slane & lb) ? -1.f : 1.f;
            #pragma unroll
            for (int g = 0; g < 32; g += 4) {
                const float2 p0 = lx2<lb>(st[g+0]);
                const float2 p1 = lx2<lb>(st[g+1]);
                const float2 p2 = lx2<lb>(st[g+2]);
                const float2 p3 = lx2<lb>(st[g+3]);
                const float2 m0 = st[g+0], m1 = st[g+1], m2 = st[g+2], m3 = st[g+3];
                sre += m0.x*p0.x + m0.y*p0.y + m1.x*p1.x + m1.y*p1.y
                     + m2.x*p2.x + m2.y*p2.y + m3.x*p3.x + m3.y*p3.y;
                smm += sgn * ((m0.x*p0.y - m0.y*p0.x) + (m1.x*p1.y - m1.y*p1.x)
                            + (m2.x*p2.y - m2.y*p2.x) + (m3.x*p3.y - m3.y*p3.x));
                szz += sgn * ((m0.x*m0.x + m0.y*m0.y - p0.x*p0.x - p0.y*p0.y)
                            + (m1.x*m1.x + m1.y*m1.y - p1.x*p1.x - p1.y*p1.y)
                            + (m2.x*m2.x + m2.y*m2.y - p2.x*p2.x - p2.y*p2.y)
                            + (m3.x*m3.x + m3.y*m3.y - p3.x*p3.x - p3.y*p3.y));
            }
            szz *= 0.5f;
        }
        sre = redAll(sre);
        smm = redAll(smm);
        szz = redAll(szz);
        if (slane == 0) {
            m_row[W]      = sre;
            m_row[10 + W] = smm;
            m_row[20 + W] = szz;
        }
        measureAll<W + 1>(st, slane, m_row);
    }
}

__global__ __launch_bounds__(192) void qsb_fused(
    const float* __restrict__ x,
    const float* __restrict__ W1, const float* __restrict__ b1, const float* __restrict__ base1,
    const float* __restrict__ W2, const float* __restrict__ b2, const float* __restrict__ base2,
    const float* __restrict__ W3, const float* __restrict__ b3, const float* __restrict__ base3,
    const float* __restrict__ ar_, const float* __restrict__ ai_,
    const float* __restrict__ br_, const float* __restrict__ bi_,
    const float* __restrict__ gr_, const float* __restrict__ gi_,
    float* __restrict__ out)
{
    const int bp    = blockIdx.x;            // batch pair: items 2bp, 2bp+1
    const int wv    = threadIdx.x >> 6;      // branch 0..2 (one wave each)
    const int lane  = threadIdx.x & 63;
    const int slane = lane & 31;             // lane within sim
    const int half  = lane >> 5;             // which batch item of the pair
    const int bi    = 2 * bp + half;

    const float* Wp   = (wv == 0) ? W1    : (wv == 1) ? W2    : W3;
    const float* bias = (wv == 0) ? b1    : (wv == 1) ? b2    : b3;
    const float* base = (wv == 0) ? base1 : (wv == 1) ? base2 : base3;

    __shared__ float2 css[3][2][NPAR];
    __shared__ float  mloc[3][2][NOUT];
    float2* cs = css[wv][half];

    // ---- params: p = sigmoid(x.W^T + bias + base) * 2pi ; store (cos,sin)(p/2) ----
    const float4* xr = reinterpret_cast<const float4*>(x + (size_t)bi * FDIM);
    #pragma unroll
    for (int it = 0; it < 4; ++it) {
        const int p = slane + 32 * it;
        if (p < NPAR) {
            const float4* wr = reinterpret_cast<const float4*>(Wp + (size_t)p * FDIM);
            float acc = 0.f;
            #pragma unroll 8
            for (int k = 0; k < FDIM / 4; ++k) {
                const float4 xv = xr[k];
                const float4 wv4 = wr[k];
                acc += xv.x*wv4.x + xv.y*wv4.y + xv.z*wv4.z + xv.w*wv4.w;
            }
            acc += bias[p] + base[p];
            const float t = TWO_PI_F / (1.f + __expf(-acc));
            float sn, cn;
            __sincosf(0.5f * t, &sn, &cn);
            cs[p] = make_float2(cn, sn);
        }
    }
    __syncthreads();

    // ---- sweep 1 folded into product-state init ----
    float2 st[32];
    {
        float2 lp = make_float2(1.f, 0.f);
        #pragma unroll
        for (int bb = 0; bb < LB; ++bb) {           // lane bit bb <-> wire 9-bb
            float2 u00, u10;
            col0(cs, 9 - bb, u00, u10);
            const float2 sel = ((slane >> bb) & 1) ? u10 : u00;
            lp = cmul(lp, sel);
        }
        float2 vr[5][2];                            // reg bit j <-> wire 4-j
        #pragma unroll
        for (int j = 0; j < 5; ++j) col0(cs, 4 - j, vr[j][0], vr[j][1]);
        #pragma unroll
        for (int a = 0; a < 32; ++a) {
            float2 t = cmul(vr[0][a & 1], vr[1][(a >> 1) & 1]);
            const float2 u = cmul(vr[2][(a >> 2) & 1], vr[3][(a >> 3) & 1]);
            t = cmul(t, u);
            t = cmul(t, vr[4][(a >> 4) & 1]);
            st[a] = cmul(t, lp);
        }
    }

    // ---- circuit (sweep 1 already folded) ----
    ringF<0>(st, slane, cs, 30);
    ringB<NQ - 1>(st, slane, cs, 40);
    layer1q<0>(st, slane, cs, 50);
    ringF<0>(st, slane, cs, 80);
    ringB<NQ - 1>(st, slane, cs, 90);

    // ---- measurements into LDS ----
    measureAll<0>(st, slane, mloc[wv][half]);
    __syncthreads();

    // ---- combine: out = |alpha*m1 + beta*m2 + gamma*m3| / norm  (2 items) ----
    if (threadIdx.x < 2 * NOUT) {
        const int item = threadIdx.x / NOUT;
        const int j    = threadIdx.x % NOUT;
        const float ar = ar_[0], ai = ai_[0];
        const float br = br_[0], bi2 = bi_[0];
        const float gr = gr_[0], gi = gi_[0];
        const float inv = 1.f / sqrtf(ar*ar + ai*ai + br*br + bi2*bi2
                                      + gr*gr + gi*gi + 1e-9f);
        const float m1 = mloc[0][item][j], m2 = mloc[1][item][j], m3 = mloc[2][item][j];
        const float re = (ar * m1 + br * m2 + gr * m3) * inv;
        const float im = (ai * m1 + bi2 * m2 + gi * m3) * inv;
        out[(size_t)(2 * bp + item) * NOUT + j] = sqrtf(re * re + im * im);
    }
}

extern "C" void kernel_launch(void* const* d_in, const int* in_sizes, int n_in,
                              void* d_out, int out_size, void* d_ws, size_t ws_size,
                              hipStream_t stream)
{
    (void)in_sizes; (void)n_in; (void)out_size; (void)d_ws; (void)ws_size;
    const float* x     = (const float*)d_in[0];
    const float* W1    = (const float*)d_in[1];
    const float* b1    = (const float*)d_in[2];
    const float* W2    = (const float*)d_in[3];
    const float* b2    = (const float*)d_in[4];
    const float* W3    = (const float*)d_in[5];
    const float* b3    = (const float*)d_in[6];
    const float* base1 = (const float*)d_in[7];
    const float* base2 = (const float*)d_in[8];
    const float* base3 = (const float*)d_in[9];
    const float* ar    = (const float*)d_in[10];
    const float* ai    = (const float*)d_in[11];
    const float* br    = (const float*)d_in[12];
    const float* bi    = (const float*)d_in[13];
    const float* gr    = (const float*)d_in[14];
    const float* gi    = (const float*)d_in[15];

    qsb_fused<<<dim3(BATCH / 2), dim3(192), 0, stream>>>(
        x, W1, b1, base1, W2, b2, base2, W3, b3, base3,
        ar, ai, br, bi, gr, gi, (float*)d_out);
}

// Round 7
// 107.651 us; speedup vs baseline: 1.2145x; 1.2145x over previous
//
#include <hip/hip_runtime.h>
#include <math.h>

#define NQ 10
#define NPAR 100
#define FDIM 256
#define BATCH 256
#define NOUT 30
#define TWO_PI_F 6.283185307179586f
#define NSLOT 8

// Round 7: 2 waves per sim. Amp index (10 bits): bits[5:0] -> lane (wires 9..4),
// bits[8:6] -> reg slot (wires 3,2,1), bit[9] -> wave half (wire 0).
// Block = 384 threads = 3 branches x 2 half-waves, grid = 256 (one per batch item,
// 1 block/CU, 1.5 waves/SIMD). Wire-0 gates (5x) + wire-0 measurement exchange
// state between the two half-waves via padded LDS (72 B/lane stride, 2-way max).
// Per-gate chain is HALF of round 5 (8 slots vs 16). Cross-lane: DPP for masks
// 1,2,8; ds_swizzle for 4,16; bpermute only for mask 32 (wire 4).

template<int MASK>
__device__ __forceinline__ float lx(float v) {
    if constexpr (MASK == 1) {
        return __int_as_float(__builtin_amdgcn_update_dpp(
            0, __float_as_int(v), 0xB1, 0xF, 0xF, true));   // quad_perm [1,0,3,2]
    } else if constexpr (MASK == 2) {
        return __int_as_float(__builtin_amdgcn_update_dpp(
            0, __float_as_int(v), 0x4E, 0xF, 0xF, true));   // quad_perm [2,3,0,1]
    } else if constexpr (MASK == 8) {
        return __int_as_float(__builtin_amdgcn_update_dpp(
            0, __float_as_int(v), 0x128, 0xF, 0xF, true));  // row_ror:8 == xor 8
    } else if constexpr (MASK == 4) {
        return __int_as_float(__builtin_amdgcn_ds_swizzle(__float_as_int(v), 0x101F));
    } else if constexpr (MASK == 16) {
        return __int_as_float(__builtin_amdgcn_ds_swizzle(__float_as_int(v), 0x401F));
    } else {
        return __shfl_xor(v, 32, 64);
    }
}

template<int MASK>
__device__ __forceinline__ float2 lx2(float2 v) {
    return make_float2(lx<MASK>(v.x), lx<MASK>(v.y));
}

__device__ __forceinline__ float2 cmul(float2 a, float2 b) {
    return make_float2(a.x*b.x - a.y*b.y, a.x*b.y + a.y*b.x);
}

struct Ctx {
    int lane;        // 0..63 within the half-wave's wave
    int W;           // wave half = amp bit 9 (wire 0)
    float2* exs;     // self exchange row (NSLOT float2, padded stride)
    float2* exp_;    // peer exchange row
};

// ---- CRX(theta): control bit BC, target bit BT; c=cos(t/2), s=sin(t/2) ----
template<int BC, int BT>
__device__ __forceinline__ void crx(float2 (&st)[NSLOT], const Ctx& cx, float c, float s)
{
    if constexpr (BT == 9) {
        // target = wave bit: LDS exchange with the partner half-wave
        if constexpr (BC >= 6) {
            constexpr int rc = 1 << (BC - 6);
            #pragma unroll
            for (int a = 0; a < NSLOT; ++a) if (a & rc) cx.exs[a] = st[a];
            __syncthreads();
            #pragma unroll
            for (int a = 0; a < NSLOT; ++a) if (a & rc) {
                const float2 p = cx.exp_[a]; const float2 m = st[a];
                st[a] = make_float2(c*m.x + s*p.y, c*m.y - s*p.x);
            }
            __syncthreads();
        } else {
            #pragma unroll
            for (int a = 0; a < NSLOT; ++a) cx.exs[a] = st[a];
            __syncthreads();
            const bool act = (cx.lane >> BC) & 1;
            const float cc = act ? c : 1.f, ss = act ? s : 0.f;
            #pragma unroll
            for (int a = 0; a < NSLOT; ++a) {
                const float2 p = cx.exp_[a]; const float2 m = st[a];
                st[a] = make_float2(cc*m.x + ss*p.y, cc*m.y - ss*p.x);
            }
            __syncthreads();
        }
    } else if constexpr (BC == 9) {
        // control = wave bit: only the W==1 half applies plain RX on target
        if (cx.W) {
            if constexpr (BT >= 6) {
                constexpr int rt = 1 << (BT - 6);
                #pragma unroll
                for (int a = 0; a < NSLOT; ++a) {
                    if (a & rt) continue;
                    const int a1 = a | rt;
                    const float2 A0 = st[a], A1 = st[a1];
                    st[a]  = make_float2(c*A0.x + s*A1.y, c*A0.y - s*A1.x);
                    st[a1] = make_float2(c*A1.x + s*A0.y, c*A1.y - s*A0.x);
                }
            } else {
                constexpr int M = 1 << BT;
                #pragma unroll
                for (int a = 0; a < NSLOT; ++a) {
                    const float2 p = lx2<M>(st[a]); const float2 m = st[a];
                    st[a] = make_float2(c*m.x + s*p.y, c*m.y - s*p.x);
                }
            }
        }
    } else if constexpr (BT >= 6) {
        constexpr int rt = 1 << (BT - 6);
        if constexpr (BC >= 6) {
            constexpr int rc = 1 << (BC - 6);
            #pragma unroll
            for (int a = 0; a < NSLOT; ++a) {
                if (!(a & rc) || (a & rt)) continue;
                const int a1 = a | rt;
                const float2 A0 = st[a], A1 = st[a1];
                st[a]  = make_float2(c*A0.x + s*A1.y, c*A0.y - s*A1.x);
                st[a1] = make_float2(c*A1.x + s*A0.y, c*A1.y - s*A0.x);
            }
        } else {
            const bool act = (cx.lane >> BC) & 1;
            const float cc = act ? c : 1.f, ss = act ? s : 0.f;
            #pragma unroll
            for (int a = 0; a < NSLOT; ++a) {
                if (a & rt) continue;
                const int a1 = a | rt;
                const float2 A0 = st[a], A1 = st[a1];
                st[a]  = make_float2(cc*A0.x + ss*A1.y, cc*A0.y - ss*A1.x);
                st[a1] = make_float2(cc*A1.x + ss*A0.y, cc*A1.y - ss*A0.x);
            }
        }
    } else {
        constexpr int M = 1 << BT;
        if constexpr (BC >= 6) {
            constexpr int rc = 1 << (BC - 6);
            #pragma unroll
            for (int a = 0; a < NSLOT; ++a) {
                if (!(a & rc)) continue;
                const float2 p = lx2<M>(st[a]); const float2 m = st[a];
                st[a] = make_float2(c*m.x + s*p.y, c*m.y - s*p.x);
            }
        } else {
            const bool act = (cx.lane >> BC) & 1;
            const float cc = act ? c : 1.f, ss = act ? s : 0.f;
            #pragma unroll
            for (int a = 0; a < NSLOT; ++a) {
                const float2 p = lx2<M>(st[a]); const float2 m = st[a];
                st[a] = make_float2(cc*m.x + ss*p.y, cc*m.y - ss*p.x);
            }
        }
    }
}

// ---- fused 1-qubit gate U = Rz*Ry*Rx on bit BIT ----
template<int BIT>
__device__ __forceinline__ void gate1q(float2 (&st)[NSLOT], const Ctx& cx,
                                       float2 u00, float2 u01, float2 u10, float2 u11)
{
    if constexpr (BIT == 9) {
        #pragma unroll
        for (int a = 0; a < NSLOT; ++a) cx.exs[a] = st[a];
        __syncthreads();
        const float2 A = cx.W ? u11 : u00;
        const float2 B = cx.W ? u10 : u01;
        #pragma unroll
        for (int a = 0; a < NSLOT; ++a) {
            const float2 m = st[a]; const float2 p = cx.exp_[a];
            st[a] = make_float2(A.x*m.x - A.y*m.y + B.x*p.x - B.y*p.y,
                                A.x*m.y + A.y*m.x + B.x*p.y + B.y*p.x);
        }
        __syncthreads();
    } else if constexpr (BIT >= 6) {
        constexpr int rb = 1 << (BIT - 6);
        #pragma unroll
        for (int a = 0; a < NSLOT; ++a) {
            if (a & rb) continue;
            const int a1 = a | rb;
            const float2 A0 = st[a], A1 = st[a1];
            float2 n0, n1;
            n0.x = u00.x*A0.x - u00.y*A0.y + u01.x*A1.x - u01.y*A1.y;
            n0.y = u00.x*A0.y + u00.y*A0.x + u01.x*A1.y + u01.y*A1.x;
            n1.x = u10.x*A0.x - u10.y*A0.y + u11.x*A1.x - u11.y*A1.y;
            n1.y = u10.x*A0.y + u10.y*A0.x + u11.x*A1.y + u11.y*A1.x;
            st[a] = n0; st[a1] = n1;
        }
    } else {
        constexpr int M = 1 << BIT;
        const bool hi = (cx.lane >> BIT) & 1;
        const float2 A = hi ? u11 : u00;
        const float2 B = hi ? u10 : u01;
        #pragma unroll
        for (int a = 0; a < NSLOT; ++a) {
            const float2 p = lx2<M>(st[a]); const float2 m = st[a];
            st[a] = make_float2(A.x*m.x - A.y*m.y + B.x*p.x - B.y*p.y,
                                A.x*m.y + A.y*m.x + B.x*p.y + B.y*p.x);
        }
    }
}

// ---- recursive circuit drivers ----
template<int Q>
__device__ __forceinline__ void layer1q(float2 (&st)[NSLOT], const Ctx& cx,
                                        const float2* cs, int idx)
{
    if constexpr (Q < NQ) {
        const float2 X = cs[idx], Y = cs[idx + 1], Z = cs[idx + 2];
        const float cx_ = X.x, sx = X.y, cy = Y.x, sy = Y.y, cz = Z.x, sz = Z.y;
        const float2 m00 = make_float2( cy*cx_,  sy*sx);
        const float2 m01 = make_float2(-sy*cx_, -cy*sx);
        const float2 m10 = make_float2( sy*cx_, -cy*sx);
        const float2 m11 = make_float2( cy*cx_, -sy*sx);
        const float2 u00 = make_float2(cz*m00.x + sz*m00.y, cz*m00.y - sz*m00.x);
        const float2 u01 = make_float2(cz*m01.x + sz*m01.y, cz*m01.y - sz*m01.x);
        const float2 u10 = make_float2(cz*m10.x - sz*m10.y, cz*m10.y + sz*m10.x);
        const float2 u11 = make_float2(cz*m11.x - sz*m11.y, cz*m11.y + sz*m11.x);
        gate1q<9 - Q>(st, cx, u00, u01, u10, u11);
        layer1q<Q + 1>(st, cx, cs, idx + 3);
    }
}

template<int Q>
__device__ __forceinline__ void ringF(float2 (&st)[NSLOT], const Ctx& cx,
                                      const float2* cs, int idx)
{
    if constexpr (Q < NQ) {
        const float2 p = cs[idx];
        crx<9 - Q, 9 - ((Q + 1) % NQ)>(st, cx, p.x, p.y);
        ringF<Q + 1>(st, cx, cs, idx + 1);
    }
}

template<int Q>
__device__ __forceinline__ void ringB(float2 (&st)[NSLOT], const Ctx& cx,
                                      const float2* cs, int idx)
{
    if constexpr (Q >= 0) {
        const float2 p = cs[idx];
        crx<9 - Q, 9 - ((Q + NQ - 1) % NQ)>(st, cx, p.x, p.y);
        ringB<Q - 1>(st, cx, cs, idx + 1);
    }
}

// ---- column 0 of fused U = Rz*Ry*Rx (product-state init; verified r3-r6) ----
__device__ __forceinline__ void col0(const float2* cs, int w, float2& u00, float2& u10)
{
    const float2 X = cs[3*w], Y = cs[3*w + 1], Z = cs[3*w + 2];
    const float cx = X.x, sx = X.y, cy = Y.x, sy = Y.y, cz = Z.x, sz = Z.y;
    const float2 m00 = make_float2(cy*cx,  sy*sx);
    const float2 m10 = make_float2(sy*cx, -cy*sx);
    u00 = make_float2(cz*m00.x + sz*m00.y, cz*m00.y - sz*m00.x);
    u10 = make_float2(cz*m10.x - sz*m10.y, cz*m10.y + sz*m10.x);
}

// ---- measurements: per-wire partials, 5-step butterfly (masks 1..16 only),
//      lanes 0 and 32 write 4 partials per value; combine sums them ----
template<int Wq>
__device__ __forceinline__ void measureAll(const float2 (&st)[NSLOT], const Ctx& cx,
                                           float* mrow /* [4][NOUT] for this branch */)
{
    if constexpr (Wq < NQ) {
        constexpr int B = 9 - Wq;
        float sre = 0.f, smm = 0.f, szz = 0.f;
        if constexpr (B == 9) {
            // wave-bit wire: exchange, then per-thread partials
            #pragma unroll
            for (int a = 0; a < NSLOT; ++a) cx.exs[a] = st[a];
            __syncthreads();
            const float sgn = cx.W ? -1.f : 1.f;
            #pragma unroll
            for (int a = 0; a < NSLOT; ++a) {
                const float2 m = st[a], p = cx.exp_[a];
                sre += m.x*p.x + m.y*p.y;                 // sum both waves = 2 Re z01
                smm += sgn * (m.x*p.y - m.y*p.x);         // sum both waves = 2 Im z01
                szz += sgn * (m.x*m.x + m.y*m.y);         // sum = Z
            }
            __syncthreads();
        } else if constexpr (B >= 6) {
            constexpr int rb = 1 << (B - 6);
            #pragma unroll
            for (int a = 0; a < NSLOT; ++a) {
                if (a & rb) continue;
                const int a1 = a | rb;
                const float2 A0 = st[a], A1 = st[a1];
                sre += A0.x*A1.x + A0.y*A1.y;
                smm += A0.x*A1.y - A0.y*A1.x;
                szz += A0.x*A0.x + A0.y*A0.y - A1.x*A1.x - A1.y*A1.y;
            }
            sre *= 2.f; smm *= 2.f;
        } else {
            constexpr int M = 1 << B;
            const float sgn = ((cx.lane >> B) & 1) ? -1.f : 1.f;
            #pragma unroll
            for (int a = 0; a < NSLOT; ++a) {
                const float2 m = st[a];
                const float2 p = lx2<M>(m);
                sre += m.x*p.x + m.y*p.y;
                smm += sgn * (m.x*p.y - m.y*p.x);
                szz += sgn * (m.x*m.x + m.y*m.y - p.x*p.x - p.y*p.y);
            }
            szz *= 0.5f;
        }
        sre += lx<1>(sre); sre += lx<2>(sre); sre += lx<4>(sre); sre += lx<8>(sre); sre += lx<16>(sre);
        smm += lx<1>(smm); smm += lx<2>(smm); smm += lx<4>(smm); smm += lx<8>(smm); smm += lx<16>(smm);
        szz += lx<1>(szz); szz += lx<2>(szz); szz += lx<4>(szz); szz += lx<8>(szz); szz += lx<16>(szz);
        if ((cx.lane & 31) == 0) {
            const int k = (cx.W << 1) | (cx.lane >> 5);   // 4 partials per value
            mrow[k * NOUT + Wq]      = sre;
            mrow[k * NOUT + 10 + Wq] = smm;
            mrow[k * NOUT + 20 + Wq] = szz;
        }
        measureAll<Wq + 1>(st, cx, mrow);
    }
}

__global__ __launch_bounds__(384) void qsb_fused(
    const float* __restrict__ x,
    const float* __restrict__ W1, const float* __restrict__ b1, const float* __restrict__ base1,
    const float* __restrict__ W2, const float* __restrict__ b2, const float* __restrict__ base2,
    const float* __restrict__ W3, const float* __restrict__ b3, const float* __restrict__ base3,
    const float* __restrict__ ar_, const float* __restrict__ ai_,
    const float* __restrict__ br_, const float* __restrict__ bi_,
    const float* __restrict__ gr_, const float* __restrict__ gi_,
    float* __restrict__ out)
{
    const int b    = blockIdx.x;             // batch item
    const int wv2  = threadIdx.x >> 6;       // 0..5
    const int br   = wv2 >> 1;               // branch
    const int W    = wv2 & 1;                // wave half (amp bit 9 / wire 0)
    const int lane = threadIdx.x & 63;
    const int lt   = (W << 6) | lane;        // branch-local thread 0..127

    const float* Wp   = (br == 0) ? W1    : (br == 1) ? W2    : W3;
    const float* bias = (br == 0) ? b1    : (br == 1) ? b2    : b3;
    const float* base = (br == 0) ? base1 : (br == 1) ? base2 : base3;

    __shared__ float2 css[3][NPAR];
    __shared__ float2 exb[3][2][64][9];      // NSLOT + 1 pad -> 72 B/lane stride
    __shared__ float  mred[3][4][NOUT];

    // ---- params: p = sigmoid(x.W^T + bias + base) * 2pi ; store (cos,sin)(p/2) ----
    if (lt < NPAR) {
        const float4* xr = reinterpret_cast<const float4*>(x + (size_t)b * FDIM);
        const float4* wr = reinterpret_cast<const float4*>(Wp + (size_t)lt * FDIM);
        float acc = 0.f;
        #pragma unroll 8
        for (int k = 0; k < FDIM / 4; ++k) {
            const float4 xv = xr[k];
            const float4 wv4 = wr[k];
            acc += xv.x*wv4.x + xv.y*wv4.y + xv.z*wv4.z + xv.w*wv4.w;
        }
        acc += bias[lt] + base[lt];
        const float t = TWO_PI_F / (1.f + __expf(-acc));
        float sn, cn;
        __sincosf(0.5f * t, &sn, &cn);
        css[br][lt] = make_float2(cn, sn);
    }
    __syncthreads();

    const float2* cs = css[br];
    Ctx cx;
    cx.lane = lane; cx.W = W;
    cx.exs  = &exb[br][W][lane][0];
    cx.exp_ = &exb[br][1 - W][lane][0];

    // ---- sweep 1 folded into product-state init ----
    float2 st[NSLOT];
    {
        float2 lp = make_float2(1.f, 0.f);
        #pragma unroll
        for (int bb = 0; bb < 6; ++bb) {            // lane bit bb <-> wire 9-bb
            float2 u00, u10;
            col0(cs, 9 - bb, u00, u10);
            lp = cmul(lp, ((lane >> bb) & 1) ? u10 : u00);
        }
        {                                           // wave bit <-> wire 0
            float2 u00, u10;
            col0(cs, 0, u00, u10);
            lp = cmul(lp, W ? u10 : u00);
        }
        float2 v0[2], v1[2], v2[2];                 // amp bits 6,7,8 <-> wires 3,2,1
        col0(cs, 3, v0[0], v0[1]);
        col0(cs, 2, v1[0], v1[1]);
        col0(cs, 1, v2[0], v2[1]);
        #pragma unroll
        for (int a = 0; a < NSLOT; ++a) {
            const float2 t = cmul(v0[a & 1], cmul(v1[(a >> 1) & 1], v2[(a >> 2) & 1]));
            st[a] = cmul(t, lp);
        }
    }

    // ---- circuit (sweep 1 already folded) ----
    ringF<0>(st, cx, cs, 30);
    ringB<NQ - 1>(st, cx, cs, 40);
    layer1q<0>(st, cx, cs, 50);
    ringF<0>(st, cx, cs, 80);
    ringB<NQ - 1>(st, cx, cs, 90);

    // ---- measurements ----
    measureAll<0>(st, cx, &mred[br][0][0]);
    __syncthreads();

    // ---- combine: out = |alpha*m1 + beta*m2 + gamma*m3| / norm ----
    if (threadIdx.x < NOUT) {
        const int j = threadIdx.x;
        const float m1 = mred[0][0][j] + mred[0][1][j] + mred[0][2][j] + mred[0][3][j];
        const float m2 = mred[1][0][j] + mred[1][1][j] + mred[1][2][j] + mred[1][3][j];
        const float m3 = mred[2][0][j] + mred[2][1][j] + mred[2][2][j] + mred[2][3][j];
        const float ar = ar_[0], ai = ai_[0];
        const float brr = br_[0], bii = bi_[0];
        const float gr = gr_[0], gi = gi_[0];
        const float inv = 1.f / sqrtf(ar*ar + ai*ai + brr*brr + bii*bii
                                      + gr*gr + gi*gi + 1e-9f);
        const float re = (ar * m1 + brr * m2 + gr * m3) * inv;
        const float im = (ai * m1 + bii * m2 + gi * m3) * inv;
        out[(size_t)b * NOUT + j] = sqrtf(re * re + im * im);
    }
}

extern "C" void kernel_launch(void* const* d_in, const int* in_sizes, int n_in,
                              void* d_out, int out_size, void* d_ws, size_t ws_size,
                              hipStream_t stream)
{
    (void)in_sizes; (void)n_in; (void)out_size; (void)d_ws; (void)ws_size;
    const float* x     = (const float*)d_in[0];
    const float* W1    = (const float*)d_in[1];
    const float* b1    = (const float*)d_in[2];
    const float* W2    = (const float*)d_in[3];
    const float* b2    = (const float*)d_in[4];
    const float* W3    = (const float*)d_in[5];
    const float* b3    = (const float*)d_in[6];
    const float* base1 = (const float*)d_in[7];
    const float* base2 = (const float*)d_in[8];
    const float* base3 = (const float*)d_in[9];
    const float* ar    = (const float*)d_in[10];
    const float* ai    = (const float*)d_in[11];
    const float* br    = (const float*)d_in[12];
    const float* bi    = (const float*)d_in[13];
    const float* gr    = (const float*)d_in[14];
    const float* gi    = (const float*)d_in[15];

    qsb_fused<<<dim3(BATCH), dim3(384), 0, stream>>>(
        x, W1, b1, base1, W2, b2, base2, W3, b3, base3,
        ar, ai, br, bi, gr, gi, (float*)d_out);
}